// Round 12
// baseline (307.697 us; speedup 1.0000x reference)
//
#include <hip/hip_runtime.h>

#define NB 128
#define NT 512
#define NL 256
#define NWG NB           // one workgroup per batch

typedef float f32x4 __attribute__((ext_vector_type(4)));
typedef int   i32x8 __attribute__((ext_vector_type(8)));
typedef int   i32x4v __attribute__((ext_vector_type(4)));

#define EASTRIDE 272     // bytes per EA buffer (256 + 16 pad, 16B aligned)
#define GEXP 7           // a-priori per-step log2 growth estimate
#define E8M0_ONE 127     // e8m0 encoding of 1.0 for mfma_scale
#define INV_LN2 1.4426950408889634f
#define LN2 0.6931471805599453f

__device__ inline float log2_fast(float x) {
#if __has_builtin(__builtin_amdgcn_logf)
    return __builtin_amdgcn_logf(x);
#else
    return __log2f(x);
#endif
}
__device__ inline float exp2_fast(float x) {
#if __has_builtin(__builtin_amdgcn_exp2f)
    return __builtin_amdgcn_exp2f(x);
#else
    return exp2f(x);
#endif
}

// Barrier that waits only on LDS ops — prefetch global loads stay in flight.
__device__ inline void barrier_lds_only() {
    asm volatile("s_waitcnt lgkmcnt(0)" ::: "memory");
    __builtin_amdgcn_s_barrier();
    asm volatile("" ::: "memory");
}

// pack 4 f32 -> 4 fp8 e4m3 bytes (saturating)
__device__ inline unsigned pk_fp8x4(float a, float b, float c, float d) {
    int w = __builtin_amdgcn_cvt_pk_fp8_f32(a, b, 0, false);
    w     = __builtin_amdgcn_cvt_pk_fp8_f32(c, d, w, true);
    return (unsigned)w;
}

// 32 contiguous LDS bytes -> v8i32 (two b128 reads)
__device__ inline i32x8 ld_b256(const unsigned char* p) {
    i32x4v lo = *reinterpret_cast<const i32x4v*>(p);
    i32x4v hi = *reinterpret_cast<const i32x4v*>(p + 16);
    i32x8 r;
    r[0] = lo[0]; r[1] = lo[1]; r[2] = lo[2]; r[3] = lo[3];
    r[4] = hi[0]; r[5] = hi[1]; r[6] = hi[2]; r[7] = hi[3];
    return r;
}

// One WG (256 thr = 4 waves) per batch.  Numerics identical to r8-r10
// (absmax 0.0): exp-space recurrence, damped power-of-2 normalization from a
// one-step-stale max, S accumulates exact integer exponents.
// Issue-model fixes (r10 post-mortem: MFMA 620 cy/SIMD at K=32 was the top
// issue-term; uniform s_load of words drained by every lgkmcnt(0) barrier):
//  * mfma_scale_f32_16x16x128_f8f6f4 (unit scales): 32 -> 8 MFMA per wave,
//    ~277 cy/SIMD.  B-frag: lane (g,b) reads ea[kt*128+g*32 .. +31] — natural
//    contiguous layout, 2x ds_read_b128 broadcast per kt, no permutation.
//  * words staged to LDS once; per-step refresh is ds_read_b32 (cheap drain).
// Layout (16x16x128, shape-determined): A row=lane&15, k=(lane>>4)*32+j;
// B col=lane&15 (batch dup), k=(lane>>4)*32+j; D col=lane&15, row=g*4+reg.
__global__ __launch_bounds__(256, 1) void crf_forward(
    const float* __restrict__ emis,
    const float* __restrict__ trans,
    const int*   __restrict__ words,
    float*       __restrict__ bout)
{
    const int tid = threadIdx.x;
    const int l   = tid & 63;
    const int wv  = tid >> 6;    // 0..3
    const int g   = l >> 4;      // 0..3
    const int b   = l & 15;

    __shared__ __align__(16) unsigned char ea[2][EASTRIDE]; // fp8 EA, dbuf
    __shared__ __align__(16) float pm[2][4];                // per-wave stale maxes
    __shared__ int wlds[NT];                                // staged word indices

    const int wrow = blockIdx.x * NT;

    // ---- stage word indices to LDS (uniform s_loads only in prologue) ----
    wlds[tid]       = words[wrow + tid];
    wlds[tid + 256] = words[wrow + tid + 256];

    // ---- A-fragments: exp(trans) rows wv*64 + T*16 + b, K=128 layout ----
    // afr[T][kt] = 32 fp8 bytes = exp(trans[row][kt*128 + g*32 .. +31])
    i32x8 afr[4][2];
    #pragma unroll
    for (int T = 0; T < 4; ++T) {
        const int row = wv * 64 + T * 16 + b;
        #pragma unroll
        for (int kt = 0; kt < 2; ++kt) {
            const float* src = trans + row * NL + kt * 128 + g * 32;
            i32x8 a;
            #pragma unroll
            for (int w = 0; w < 8; ++w) {
                float4 v = *reinterpret_cast<const float4*>(src + w * 4);
                a[w] = (int)pk_fp8x4(__expf(v.x), __expf(v.y),
                                     __expf(v.z), __expf(v.w));
            }
            afr[T][kt] = a;
        }
    }

    // ---- word pipeline (prologue: direct reads; steady: wlds ds_read) ----
    const int w0 = words[wrow + 0];
    const int w1 = words[wrow + 1];
    const int w2 = words[wrow + 2];
    const int w3 = words[wrow + 3];
    const int w4 = words[wrow + 4];
    int wregA = words[wrow + 5];
    int wregB = words[wrow + 6];
    int wregC = words[wrow + 7];
    int wregD = words[wrow + 8];

    float S = 0.f;   // exponent accumulator (exact small ints, same in all lanes)

    // ---- t=0 : EA_0 = fp8(2^(e0*INV_LN2)), rows wv*64 + T*16 + g*4 + j ----
    {
        const float* e0 = emis + (size_t)w0 * NL + wv * 64 + g * 4;
        float pmax = 0.f;
        unsigned pk[4];
        #pragma unroll
        for (int T = 0; T < 4; ++T) {
            f32x4 v = *reinterpret_cast<const f32x4*>(e0 + T * 16);
            float p0 = exp2_fast(v[0] * INV_LN2);
            float p1 = exp2_fast(v[1] * INV_LN2);
            float p2 = exp2_fast(v[2] * INV_LN2);
            float p3 = exp2_fast(v[3] * INV_LN2);
            pmax = fmaxf(pmax, fmaxf(fmaxf(p0, p1), fmaxf(p2, p3)));
            pk[T] = pk_fp8x4(p0, p1, p2, p3);
        }
        pmax = fmaxf(pmax, __shfl_xor(pmax, 16));
        pmax = fmaxf(pmax, __shfl_xor(pmax, 32));
        if (l == 0) pm[0][wv] = pmax;
        if (b == 0) {
            #pragma unroll
            for (int T = 0; T < 4; ++T)
                *reinterpret_cast<unsigned*>(&ea[0][wv * 64 + T * 16 + g * 4]) = pk[T];
        }
    }
    f32x4 pfA[4], pfB[4], pfC[4], pfD[4];
    {
        const float* p;
        p = emis + (size_t)w1 * NL + wv * 64 + g * 4;
        pfA[0] = *(const f32x4*)p; pfA[1] = *(const f32x4*)(p + 16);
        pfA[2] = *(const f32x4*)(p + 32); pfA[3] = *(const f32x4*)(p + 48);
        p = emis + (size_t)w2 * NL + wv * 64 + g * 4;
        pfB[0] = *(const f32x4*)p; pfB[1] = *(const f32x4*)(p + 16);
        pfB[2] = *(const f32x4*)(p + 32); pfB[3] = *(const f32x4*)(p + 48);
        p = emis + (size_t)w3 * NL + wv * 64 + g * 4;
        pfC[0] = *(const f32x4*)p; pfC[1] = *(const f32x4*)(p + 16);
        pfC[2] = *(const f32x4*)(p + 32); pfC[3] = *(const f32x4*)(p + 48);
        p = emis + (size_t)w4 * NL + wv * 64 + g * 4;
        pfD[0] = *(const f32x4*)p; pfD[1] = *(const f32x4*)(p + 16);
        pfD[2] = *(const f32x4*)(p + 32); pfD[3] = *(const f32x4*)(p + 48);
    }
    barrier_lds_only();

#define CRF_STEP(t, RD, WR, PF, WREG)                                           \
    {                                                                           \
        /* B-frags: natural contiguous, broadcast b128 reads */                 \
        i32x8 bq0 = ld_b256(&ea[RD][g * 32]);                                   \
        i32x8 bq1 = ld_b256(&ea[RD][128 + g * 32]);                             \
        f32x4 pmv = *reinterpret_cast<const f32x4*>(&pm[RD][0]);                \
        float gm  = fmaxf(fmaxf(pmv[0], pmv[1]), fmaxf(pmv[2], pmv[3]));        \
        int   kb  = (int)(__builtin_bit_cast(unsigned, gm) >> 23) - (127 - GEXP);\
        S += (float)kb;                                                         \
        float kbf = (float)kb;                                                  \
        f32x4 eC[4] = { PF[0], PF[1], PF[2], PF[3] };                           \
        if ((t) + 4 < NT) {                                                     \
            const float* ep = emis + (size_t)WREG * NL + wv * 64 + g * 4;       \
            PF[0] = *(const f32x4*)ep;        PF[1] = *(const f32x4*)(ep + 16); \
            PF[2] = *(const f32x4*)(ep + 32); PF[3] = *(const f32x4*)(ep + 48); \
        }                                                                       \
        if ((t) + 8 < NT) WREG = wlds[(t) + 8];                                 \
        /* ex hides under lgkm/MFMA wait */                                     \
        f32x4 ex[4];                                                            \
        _Pragma("unroll")                                                       \
        for (int T = 0; T < 4; ++T) {                                           \
            ex[T][0] = exp2_fast(fmaf(eC[T][0], INV_LN2, -kbf));                \
            ex[T][1] = exp2_fast(fmaf(eC[T][1], INV_LN2, -kbf));                \
            ex[T][2] = exp2_fast(fmaf(eC[T][2], INV_LN2, -kbf));                \
            ex[T][3] = exp2_fast(fmaf(eC[T][3], INV_LN2, -kbf));                \
        }                                                                       \
        /* 4 independent depth-2 scale-MFMA chains (K=128 each) */              \
        f32x4 sA[4];                                                            \
        _Pragma("unroll")                                                       \
        for (int T = 0; T < 4; ++T) {                                           \
            f32x4 z = {0.f, 0.f, 0.f, 0.f};                                     \
            z = __builtin_amdgcn_mfma_scale_f32_16x16x128_f8f6f4(               \
                    afr[T][0], bq0, z, 0, 0, 0, E8M0_ONE, 0, E8M0_ONE);         \
            z = __builtin_amdgcn_mfma_scale_f32_16x16x128_f8f6f4(               \
                    afr[T][1], bq1, z, 0, 0, 0, E8M0_ONE, 0, E8M0_ONE);         \
            sA[T] = z;                                                          \
        }                                                                       \
        float pmax = 0.f;                                                       \
        unsigned pk[4];                                                         \
        _Pragma("unroll")                                                       \
        for (int T = 0; T < 4; ++T) {                                           \
            f32x4 wv4 = sA[T] * ex[T];                                          \
            pmax = fmaxf(pmax, fmaxf(fmaxf(wv4[0], wv4[1]),                     \
                                     fmaxf(wv4[2], wv4[3])));                   \
            pk[T] = pk_fp8x4(wv4[0], wv4[1], wv4[2], wv4[3]);                   \
        }                                                                       \
        pmax = fmaxf(pmax, __shfl_xor(pmax, 16));                               \
        pmax = fmaxf(pmax, __shfl_xor(pmax, 32));                               \
        if (l == 0) pm[WR][wv] = pmax;                                          \
        if (b == 0) {                                                           \
            _Pragma("unroll")                                                   \
            for (int T = 0; T < 4; ++T)                                         \
                *reinterpret_cast<unsigned*>(                                   \
                    &ea[WR][wv * 64 + T * 16 + g * 4]) = pk[T];                 \
        }                                                                       \
        barrier_lds_only();                                                     \
    }

    int t = 1;
    for (; t + 3 < NT; t += 4) {
        CRF_STEP(t,     0, 1, pfA, wregA);
        CRF_STEP(t + 1, 1, 0, pfB, wregB);
        CRF_STEP(t + 2, 0, 1, pfC, wregC);
        CRF_STEP(t + 3, 1, 0, pfD, wregD);
    }
    // tail: t = 509, 510, 511  (parity: WR = t&1; final EA lands in ea[1])
    CRF_STEP(509, 0, 1, pfA, wregA);
    CRF_STEP(510, 1, 0, pfB, wregB);
    CRF_STEP(511, 0, 1, pfC, wregC);
#undef CRF_STEP

    // ---- final: logZ_b = ln2 * (S + log2(sum_k EA_last[k])) ----
    if (tid < 64) {
        unsigned u = *reinterpret_cast<const unsigned*>(&ea[1][tid * 4]);
        float s = __builtin_amdgcn_cvt_f32_fp8((int)u, 0)
                + __builtin_amdgcn_cvt_f32_fp8((int)u, 1)
                + __builtin_amdgcn_cvt_f32_fp8((int)u, 2)
                + __builtin_amdgcn_cvt_f32_fp8((int)u, 3);
        #pragma unroll
        for (int off = 32; off; off >>= 1) s += __shfl_xor(s, off);
        if (tid == 0) bout[blockIdx.x] = (S + log2_fast(s)) * LN2;
    }
}

__global__ void crf_reduce(const float* __restrict__ bout, float* __restrict__ out)
{
    const int tid = threadIdx.x;  // 128 threads
    float v = bout[tid];
    #pragma unroll
    for (int off = 32; off; off >>= 1) v += __shfl_xor(v, off);
    __shared__ float sred[2];
    if ((tid & 63) == 0) sred[tid >> 6] = v;
    __syncthreads();
    if (tid == 0) out[0] = sred[0] + sred[1];
}

extern "C" void kernel_launch(void* const* d_in, const int* in_sizes, int n_in,
                              void* d_out, int out_size, void* d_ws, size_t ws_size,
                              hipStream_t stream)
{
    const float* emis  = (const float*)d_in[0];
    const float* trans = (const float*)d_in[1];
    const int*   words = (const int*)d_in[2];
    float* out  = (float*)d_out;
    float* bout = (float*)d_ws;   // NWG floats of scratch

    crf_forward<<<NWG, 256, 0, stream>>>(emis, trans, words, bout);
    crf_reduce<<<1, NB, 0, stream>>>(bout, out);
}

// Round 13
// 293.180 us; speedup vs baseline: 1.0495x; 1.0495x over previous
//
#include <hip/hip_runtime.h>

#define NB 128
#define NT 512
#define NL 256
#define NWG NB           // one workgroup per batch

typedef float f32x4 __attribute__((ext_vector_type(4)));
typedef int   i32x8 __attribute__((ext_vector_type(8)));
typedef int   i32x4v __attribute__((ext_vector_type(4)));

#define EASTRIDE 272     // bytes per EA buffer (256 + 16 pad, 16B aligned)
#define GEXP 7           // a-priori per-step log2 growth estimate
#define E8M0_ONE 127     // e8m0 encoding of 1.0 for mfma_scale
#define INV_LN2 1.4426950408889634f
#define LN2 0.6931471805599453f

__device__ inline float log2_fast(float x) {
#if __has_builtin(__builtin_amdgcn_logf)
    return __builtin_amdgcn_logf(x);
#else
    return __log2f(x);
#endif
}
__device__ inline float exp2_fast(float x) {
#if __has_builtin(__builtin_amdgcn_exp2f)
    return __builtin_amdgcn_exp2f(x);
#else
    return exp2f(x);
#endif
}

// Barrier that waits only on LDS ops — prefetch global loads stay in flight.
__device__ inline void barrier_lds_only() {
    asm volatile("s_waitcnt lgkmcnt(0)" ::: "memory");
    __builtin_amdgcn_s_barrier();
    asm volatile("" ::: "memory");
}

// pack 4 f32 -> 4 fp8 e4m3 bytes (saturating)
__device__ inline unsigned pk_fp8x4(float a, float b, float c, float d) {
    int w = __builtin_amdgcn_cvt_pk_fp8_f32(a, b, 0, false);
    w     = __builtin_amdgcn_cvt_pk_fp8_f32(c, d, w, true);
    return (unsigned)w;
}

// 32 contiguous LDS bytes -> v8i32 (two b128 reads)
__device__ inline i32x8 ld_b256(const unsigned char* p) {
    i32x4v lo = *reinterpret_cast<const i32x4v*>(p);
    i32x4v hi = *reinterpret_cast<const i32x4v*>(p + 16);
    i32x8 r;
    r[0] = lo[0]; r[1] = lo[1]; r[2] = lo[2]; r[3] = lo[3];
    r[4] = hi[0]; r[5] = hi[1]; r[6] = hi[2]; r[7] = hi[3];
    return r;
}

// One WG (512 thr = 8 waves, 2 waves/SIMD) per batch.  Numerics identical to
// r8-r12 (absmax 0.0): exp-space recurrence, damped power-of-2 normalization
// from a one-step-stale max, S accumulates exact integer exponents.
// r12 post-mortem: 1 wave/SIMD left ~570 cy/step of exposed dependency
// latency.  Fix: 8 waves (each owns 32 rows = 2 i-tiles), so two co-resident
// waves per SIMD interleave; per-SIMD MFMA issue unchanged (2x4 K=128
// scale-MFMA), per-wave VALU halves (8 exp2/thread).
// Layout (16x16x128, shape-determined): A row=lane&15, k=(lane>>4)*32+j;
// B col=lane&15 (batch dup), k=(lane>>4)*32+j; D col=lane&15, row=g*4+reg.
__global__ __launch_bounds__(512, 2) void crf_forward(
    const float* __restrict__ emis,
    const float* __restrict__ trans,
    const int*   __restrict__ words,
    float*       __restrict__ bout)
{
    const int tid = threadIdx.x;
    const int l   = tid & 63;
    const int wv  = tid >> 6;    // 0..7
    const int g   = l >> 4;      // 0..3
    const int b   = l & 15;

    __shared__ __align__(16) unsigned char ea[2][EASTRIDE]; // fp8 EA, dbuf
    __shared__ __align__(16) float pm[2][8];                // per-wave stale maxes
    __shared__ int wlds[NT];                                // staged word indices

    const int wrow = blockIdx.x * NT;

    // ---- stage word indices to LDS ----
    wlds[tid] = words[wrow + tid];

    // ---- A-fragments: exp(trans) rows wv*32 + T*16 + b, K=128 layout ----
    i32x8 afr[2][2];
    #pragma unroll
    for (int T = 0; T < 2; ++T) {
        const int row = wv * 32 + T * 16 + b;
        #pragma unroll
        for (int kt = 0; kt < 2; ++kt) {
            const float* src = trans + row * NL + kt * 128 + g * 32;
            i32x8 a;
            #pragma unroll
            for (int w = 0; w < 8; ++w) {
                float4 v = *reinterpret_cast<const float4*>(src + w * 4);
                a[w] = (int)pk_fp8x4(__expf(v.x), __expf(v.y),
                                     __expf(v.z), __expf(v.w));
            }
            afr[T][kt] = a;
        }
    }

    // ---- word pipeline (prologue direct; steady: wlds ds_read) ----
    const int w0 = words[wrow + 0];
    const int w1 = words[wrow + 1];
    const int w2 = words[wrow + 2];
    const int w3 = words[wrow + 3];
    const int w4 = words[wrow + 4];
    int wregA = words[wrow + 5];
    int wregB = words[wrow + 6];
    int wregC = words[wrow + 7];
    int wregD = words[wrow + 8];

    float S = 0.f;   // exponent accumulator (exact small ints, same in all lanes)

    // ---- t=0 : EA_0 = fp8(2^(e0*INV_LN2)), rows wv*32 + T*16 + g*4 + j ----
    {
        const float* e0 = emis + (size_t)w0 * NL + wv * 32 + g * 4;
        float pmax = 0.f;
        unsigned pk[2];
        #pragma unroll
        for (int T = 0; T < 2; ++T) {
            f32x4 v = *reinterpret_cast<const f32x4*>(e0 + T * 16);
            float p0 = exp2_fast(v[0] * INV_LN2);
            float p1 = exp2_fast(v[1] * INV_LN2);
            float p2 = exp2_fast(v[2] * INV_LN2);
            float p3 = exp2_fast(v[3] * INV_LN2);
            pmax = fmaxf(pmax, fmaxf(fmaxf(p0, p1), fmaxf(p2, p3)));
            pk[T] = pk_fp8x4(p0, p1, p2, p3);
        }
        pmax = fmaxf(pmax, __shfl_xor(pmax, 16));
        pmax = fmaxf(pmax, __shfl_xor(pmax, 32));
        if (l == 0) pm[0][wv] = pmax;
        if (b == 0) {
            *reinterpret_cast<unsigned*>(&ea[0][wv * 32 + g * 4])      = pk[0];
            *reinterpret_cast<unsigned*>(&ea[0][wv * 32 + 16 + g * 4]) = pk[1];
        }
    }
    f32x4 pfA[2], pfB[2], pfC[2], pfD[2];
    {
        const float* p;
        p = emis + (size_t)w1 * NL + wv * 32 + g * 4;
        pfA[0] = *(const f32x4*)p; pfA[1] = *(const f32x4*)(p + 16);
        p = emis + (size_t)w2 * NL + wv * 32 + g * 4;
        pfB[0] = *(const f32x4*)p; pfB[1] = *(const f32x4*)(p + 16);
        p = emis + (size_t)w3 * NL + wv * 32 + g * 4;
        pfC[0] = *(const f32x4*)p; pfC[1] = *(const f32x4*)(p + 16);
        p = emis + (size_t)w4 * NL + wv * 32 + g * 4;
        pfD[0] = *(const f32x4*)p; pfD[1] = *(const f32x4*)(p + 16);
    }
    barrier_lds_only();

#define CRF_STEP(t, RD, WR, PF, WREG)                                           \
    {                                                                           \
        /* B-frags: natural contiguous, broadcast b128 reads */                 \
        i32x8 bq0 = ld_b256(&ea[RD][g * 32]);                                   \
        i32x8 bq1 = ld_b256(&ea[RD][128 + g * 32]);                             \
        f32x4 pm0 = *reinterpret_cast<const f32x4*>(&pm[RD][0]);                \
        f32x4 pm1 = *reinterpret_cast<const f32x4*>(&pm[RD][4]);                \
        float gm  = fmaxf(fmaxf(fmaxf(pm0[0], pm0[1]), fmaxf(pm0[2], pm0[3])),  \
                          fmaxf(fmaxf(pm1[0], pm1[1]), fmaxf(pm1[2], pm1[3]))); \
        int   kb  = (int)(__builtin_bit_cast(unsigned, gm) >> 23) - (127 - GEXP);\
        S += (float)kb;                                                         \
        float kbf = (float)kb;                                                  \
        f32x4 eC[2] = { PF[0], PF[1] };                                         \
        if ((t) + 4 < NT) {                                                     \
            const float* ep = emis + (size_t)WREG * NL + wv * 32 + g * 4;       \
            PF[0] = *(const f32x4*)ep;  PF[1] = *(const f32x4*)(ep + 16);       \
        }                                                                       \
        if ((t) + 8 < NT) WREG = wlds[(t) + 8];                                 \
        /* ex hides under lgkm/MFMA wait */                                     \
        f32x4 ex[2];                                                            \
        _Pragma("unroll")                                                       \
        for (int T = 0; T < 2; ++T) {                                           \
            ex[T][0] = exp2_fast(fmaf(eC[T][0], INV_LN2, -kbf));                \
            ex[T][1] = exp2_fast(fmaf(eC[T][1], INV_LN2, -kbf));                \
            ex[T][2] = exp2_fast(fmaf(eC[T][2], INV_LN2, -kbf));                \
            ex[T][3] = exp2_fast(fmaf(eC[T][3], INV_LN2, -kbf));                \
        }                                                                       \
        /* 2 independent depth-2 scale-MFMA chains (K=128 each) */              \
        f32x4 sA[2];                                                            \
        _Pragma("unroll")                                                       \
        for (int T = 0; T < 2; ++T) {                                           \
            f32x4 z = {0.f, 0.f, 0.f, 0.f};                                     \
            z = __builtin_amdgcn_mfma_scale_f32_16x16x128_f8f6f4(               \
                    afr[T][0], bq0, z, 0, 0, 0, E8M0_ONE, 0, E8M0_ONE);         \
            z = __builtin_amdgcn_mfma_scale_f32_16x16x128_f8f6f4(               \
                    afr[T][1], bq1, z, 0, 0, 0, E8M0_ONE, 0, E8M0_ONE);         \
            sA[T] = z;                                                          \
        }                                                                       \
        float pmax = 0.f;                                                       \
        unsigned pk[2];                                                         \
        _Pragma("unroll")                                                       \
        for (int T = 0; T < 2; ++T) {                                           \
            f32x4 wv4 = sA[T] * ex[T];                                          \
            pmax = fmaxf(pmax, fmaxf(fmaxf(wv4[0], wv4[1]),                     \
                                     fmaxf(wv4[2], wv4[3])));                   \
            pk[T] = pk_fp8x4(wv4[0], wv4[1], wv4[2], wv4[3]);                   \
        }                                                                       \
        pmax = fmaxf(pmax, __shfl_xor(pmax, 16));                               \
        pmax = fmaxf(pmax, __shfl_xor(pmax, 32));                               \
        if (l == 0) pm[WR][wv] = pmax;                                          \
        if (b == 0) {                                                           \
            *reinterpret_cast<unsigned*>(&ea[WR][wv * 32 + g * 4])      = pk[0];\
            *reinterpret_cast<unsigned*>(&ea[WR][wv * 32 + 16 + g * 4]) = pk[1];\
        }                                                                       \
        barrier_lds_only();                                                     \
    }

    int t = 1;
    for (; t + 3 < NT; t += 4) {
        CRF_STEP(t,     0, 1, pfA, wregA);
        CRF_STEP(t + 1, 1, 0, pfB, wregB);
        CRF_STEP(t + 2, 0, 1, pfC, wregC);
        CRF_STEP(t + 3, 1, 0, pfD, wregD);
    }
    // tail: t = 509, 510, 511  (parity: final EA lands in ea[1])
    CRF_STEP(509, 0, 1, pfA, wregA);
    CRF_STEP(510, 1, 0, pfB, wregB);
    CRF_STEP(511, 0, 1, pfC, wregC);
#undef CRF_STEP

    // ---- final: logZ_b = ln2 * (S + log2(sum_k EA_last[k])) ----
    if (tid < 64) {
        unsigned u = *reinterpret_cast<const unsigned*>(&ea[1][tid * 4]);
        float s = __builtin_amdgcn_cvt_f32_fp8((int)u, 0)
                + __builtin_amdgcn_cvt_f32_fp8((int)u, 1)
                + __builtin_amdgcn_cvt_f32_fp8((int)u, 2)
                + __builtin_amdgcn_cvt_f32_fp8((int)u, 3);
        #pragma unroll
        for (int off = 32; off; off >>= 1) s += __shfl_xor(s, off);
        if (tid == 0) bout[blockIdx.x] = (S + log2_fast(s)) * LN2;
    }
}

__global__ void crf_reduce(const float* __restrict__ bout, float* __restrict__ out)
{
    const int tid = threadIdx.x;  // 128 threads
    float v = bout[tid];
    #pragma unroll
    for (int off = 32; off; off >>= 1) v += __shfl_xor(v, off);
    __shared__ float sred[2];
    if ((tid & 63) == 0) sred[tid >> 6] = v;
    __syncthreads();
    if (tid == 0) out[0] = sred[0] + sred[1];
}

extern "C" void kernel_launch(void* const* d_in, const int* in_sizes, int n_in,
                              void* d_out, int out_size, void* d_ws, size_t ws_size,
                              hipStream_t stream)
{
    const float* emis  = (const float*)d_in[0];
    const float* trans = (const float*)d_in[1];
    const int*   words = (const int*)d_in[2];
    float* out  = (float*)d_out;
    float* bout = (float*)d_ws;   // NWG floats of scratch

    crf_forward<<<NWG, 512, 0, stream>>>(emis, trans, words, bout);
    crf_reduce<<<1, NB, 0, stream>>>(bout, out);
}